// Round 1
// baseline (99.412 us; speedup 1.0000x reference)
//
#include <hip/hip_runtime.h>
#include <hip/hip_bf16.h>
#include <math.h>

// Problem constants (from setup_inputs)
#define BB  4
#define TT  8192
#define DD  64
#define PP  8
#define CC  32            // chunk length along t
#define NCH (TT/CC)       // 256 chunks
#define AGG_STRIDE 130    // 64 cos-d + 64 sin-d + cosK + sinK

__device__ __constant__ float kPI4 = 0.78539816339744830962f;
#define EPSV 1e-3f

// ---------------- Pass 1: per-(b,p,chunk) aggregates in d-space ------------
// agg[(b*PP+p)*NCH + c][0..63]  = sum_t cos(k[t]) * Q[t,i]
// agg[...][64..127]             = sum_t sin(k[t]) * Q[t,i]
// agg[...][128],[129]           = sum_t cos(k[t]), sum_t sin(k[t])
__global__ __launch_bounds__(64) void k_pass1(const float* __restrict__ q,
                                              const float* __restrict__ Wk,
                                              float* __restrict__ agg) {
  const int blk = blockIdx.x;                 // (b*PP+p)*NCH + c
  const int c  = blk & (NCH - 1);
  const int pp = (blk >> 8) & (PP - 1);
  const int b  = blk >> 11;

  __shared__ float Qs[CC * 65];
  __shared__ float cks[CC], sks[CC];

  const float* qb = q + ((size_t)b * TT + (size_t)c * CC) * DD;
  const int tid = threadIdx.x;

  for (int g = tid; g < CC * DD; g += 64)
    Qs[(g >> 6) * 65 + (g & 63)] = qb[g];
  __syncthreads();

  if (tid < CC) {
    const float* wk = Wk + pp * DD;
    float dk = 0.f;
#pragma unroll
    for (int i = 0; i < DD; ++i) dk = fmaf(Qs[tid * 65 + i], wk[i], dk);
    float kv = tanhf(dk) * kPI4;
    float s, co;
    sincosf(kv, &s, &co);
    cks[tid] = co;
    sks[tid] = s;
  }
  __syncthreads();

  float cc = 0.f, ss = 0.f;
#pragma unroll
  for (int t = 0; t < CC; ++t) {
    float qv = Qs[t * 65 + tid];
    cc = fmaf(cks[t], qv, cc);
    ss = fmaf(sks[t], qv, ss);
  }
  float* a = agg + (size_t)((b * PP + pp) * NCH + c) * AGG_STRIDE;
  a[tid] = cc;
  a[64 + tid] = ss;
  if (tid == 0) { float s2 = 0.f; for (int t = 0; t < CC; ++t) s2 += cks[t]; a[128] = s2; }
  if (tid == 1) { float s2 = 0.f; for (int t = 0; t < CC; ++t) s2 += sks[t]; a[129] = s2; }
}

// ---------------- Pass 2: exclusive scan over chunks, in place -------------
__global__ __launch_bounds__(256) void k_pass2(float* __restrict__ agg) {
  const int bp = blockIdx.x;  // b*PP+p, 0..31
  const int j = threadIdx.x;
  if (j >= AGG_STRIDE) return;
  size_t base = (size_t)bp * NCH * AGG_STRIDE + j;
  float run = 0.f;
  for (int c = 0; c < NCH; ++c) {
    size_t idx = base + (size_t)c * AGG_STRIDE;
    float v = agg[idx];
    agg[idx] = run;
    run += v;
  }
}

// ---------------- Pass 3: scan + fused Z @ Wv GEMM -------------------------
__global__ __launch_bounds__(256) void k_pass3(
    const float* __restrict__ q, const float* __restrict__ Wq,
    const float* __restrict__ Wk, const float* __restrict__ Wv,
    const float* __restrict__ Wo, const float* __restrict__ pref,
    float* __restrict__ out) {
  const int blk = blockIdx.x;    // b*NCH + c
  const int c = blk & (NCH - 1);
  const int b = blk >> 8;

  __shared__ float Qs[CC * 65];                            // 8.32 KB
  __shared__ float cqs[PP * CC], sqs[PP * CC];             // 2 KB
  __shared__ float cks[PP * CC], sks[PP * CC];             // 2 KB
  __shared__ float cKs[PP * CC], sKs[PP * CC];             // 2 KB
  __shared__ float Zs[CC * 513];                           // 65.7 KB

  const int tid = threadIdx.x;
  const float* qb = q + ((size_t)b * TT + (size_t)c * CC) * DD;
  for (int g = tid; g < CC * DD; g += 256)
    Qs[(g >> 6) * 65 + (g & 63)] = qb[g];
  __syncthreads();

  // Phase A: trig for all (t,p). 256 tasks, 1 per thread.
  {
    const int t = tid & (CC - 1);
    const int p = tid >> 5;
    const float* wq = Wq + p * DD;
    const float* wk = Wk + p * DD;
    float dq = 0.f, dk = 0.f;
#pragma unroll
    for (int i = 0; i < DD; ++i) {
      float qv = Qs[t * 65 + i];
      dq = fmaf(qv, wq[i], dq);
      dk = fmaf(qv, wk[i], dk);
    }
    float qa = tanhf(dq) * kPI4, ka = tanhf(dk) * kPI4;
    float s0, c0;
    sincosf(qa, &s0, &c0); cqs[p * CC + t] = c0; sqs[p * CC + t] = s0;
    sincosf(ka, &s0, &c0); cks[p * CC + t] = c0; sks[p * CC + t] = s0;
  }
  __syncthreads();

  // Phase A2: scalar inclusive cumsums of cos_k/sin_k (+ chunk prefix), per p.
  if (tid < PP) {
    const int p = tid;
    const float* pr = pref + (size_t)((b * PP + p) * NCH + c) * AGG_STRIDE;
    float rc = pr[128], rs = pr[129];
    for (int t = 0; t < CC; ++t) {
      rc += cks[p * CC + t];
      rs += sks[p * CC + t];
      cKs[p * CC + t] = rc;
      sKs[p * CC + t] = rs;
    }
  }
  __syncthreads();

  // Phase B: d-space running prefix + Z build. thread = (i, p-pair).
  {
    const int i = tid & 63;
    const int p0 = tid >> 6;  // 0..3
    const int p1 = p0 + 4;
    const float* pr0 = pref + (size_t)((b * PP + p0) * NCH + c) * AGG_STRIDE;
    const float* pr1 = pref + (size_t)((b * PP + p1) * NCH + c) * AGG_STRIDE;
    float Ac0 = pr0[i], As0 = pr0[64 + i];
    float Ac1 = pr1[i], As1 = pr1[64 + i];
    const float wo0 = Wo[p0], wo1 = Wo[p1];
    for (int t = 0; t < CC; ++t) {
      const float qv = Qs[t * 65 + i];
      {
        float ck = cks[p0 * CC + t], sk = sks[p0 * CC + t];
        Ac0 = fmaf(ck, qv, Ac0);
        As0 = fmaf(sk, qv, As0);
        float cq = cqs[p0 * CC + t], sq = sqs[p0 * CC + t];
        float den = fmaf(cq, cKs[p0 * CC + t], fmaf(sq, sKs[p0 * CC + t], EPSV));
        Zs[t * 513 + (p0 << 6) + i] = (wo0 / den) * fmaf(cq, Ac0, sq * As0);
      }
      {
        float ck = cks[p1 * CC + t], sk = sks[p1 * CC + t];
        Ac1 = fmaf(ck, qv, Ac1);
        As1 = fmaf(sk, qv, As1);
        float cq = cqs[p1 * CC + t], sq = sqs[p1 * CC + t];
        float den = fmaf(cq, cKs[p1 * CC + t], fmaf(sq, sKs[p1 * CC + t], EPSV));
        Zs[t * 513 + (p1 << 6) + i] = (wo1 / den) * fmaf(cq, Ac1, sq * As1);
      }
    }
  }
  __syncthreads();

  // Phase C: out[32x64] = Z[32x512] @ Wv[512x64], f32 VALU, 2x4 register tile.
  {
    const int t2 = tid >> 4;  // 0..15 -> rows t2*2, t2*2+1
    const int o4 = tid & 15;  // 0..15 -> cols o4*4 .. +3
    float a00 = 0, a01 = 0, a02 = 0, a03 = 0;
    float a10 = 0, a11 = 0, a12 = 0, a13 = 0;
    const float* wvb = Wv + o4 * 4;
    const int r0 = (t2 * 2) * 513, r1 = (t2 * 2 + 1) * 513;
    for (int k2 = 0; k2 < 512; ++k2) {
      float z0 = Zs[r0 + k2];
      float z1 = Zs[r1 + k2];
      float4 wv = *reinterpret_cast<const float4*>(wvb + (size_t)k2 * 64);
      a00 = fmaf(z0, wv.x, a00); a01 = fmaf(z0, wv.y, a01);
      a02 = fmaf(z0, wv.z, a02); a03 = fmaf(z0, wv.w, a03);
      a10 = fmaf(z1, wv.x, a10); a11 = fmaf(z1, wv.y, a11);
      a12 = fmaf(z1, wv.z, a12); a13 = fmaf(z1, wv.w, a13);
    }
    float* ob = out + ((size_t)b * TT + (size_t)c * CC + t2 * 2) * DD + o4 * 4;
    *reinterpret_cast<float4*>(ob) = make_float4(a00, a01, a02, a03);
    *reinterpret_cast<float4*>(ob + DD) = make_float4(a10, a11, a12, a13);
  }
}

extern "C" void kernel_launch(void* const* d_in, const int* in_sizes, int n_in,
                              void* d_out, int out_size, void* d_ws, size_t ws_size,
                              hipStream_t stream) {
  const float* q  = (const float*)d_in[0];
  const float* Wq = (const float*)d_in[1];
  const float* Wk = (const float*)d_in[2];
  const float* Wv = (const float*)d_in[3];
  const float* Wo = (const float*)d_in[4];
  float* out = (float*)d_out;
  float* agg = (float*)d_ws;  // needs BB*PP*NCH*130 floats = ~4.06 MiB

  k_pass1<<<BB * PP * NCH, 64, 0, stream>>>(q, Wk, agg);
  k_pass2<<<BB * PP, 256, 0, stream>>>(agg);
  k_pass3<<<BB * NCH, 256, 0, stream>>>(q, Wq, Wk, Wv, Wo, agg, out);
}

// Round 3
// 69.037 us; speedup vs baseline: 1.4400x; 1.4400x over previous
//
#include <hip/hip_runtime.h>
#include <hip/hip_bf16.h>
#include <math.h>

#define BB  4
#define TT  8192
#define DD  64
#define PP  8
#define CC  32            // chunk length along t
#define NCH (TT/CC)       // 256 chunks
#define AGG_STRIDE 130    // 64 cos-d + 64 sin-d + cosK + sinK
#define QSTR 68           // padded Q row stride (floats), 16B-aligned rows
#define TSTR 33           // padded per-p trig stride
#define ZSTR 264          // padded Z half-row stride (shorts): 256+8

#define EPSV 1e-3f
#define KPI4 0.78539816339744830962f

typedef __attribute__((ext_vector_type(8))) short short8;   // 8 bf16
typedef __attribute__((ext_vector_type(4))) float f32x4;

__device__ __forceinline__ unsigned short f2bf(float f) {   // f32 -> bf16 RNE
  unsigned u = __float_as_uint(f);
  u += 0x7fffu + ((u >> 16) & 1u);
  return (unsigned short)(u >> 16);
}
__device__ __forceinline__ float bf2f(unsigned short h) {
  return __uint_as_float(((unsigned)h) << 16);
}
__device__ __forceinline__ float fast_tanh(float x) {
  // tanh(x) = 1 - 2/(e^{2x}+1); inf-safe at both ends
  float e = __expf(2.f * x);
  return 1.f - 2.f * __builtin_amdgcn_rcpf(e + 1.f);
}

// ---- Pass 1: per-(b,chunk) aggregates; blocks 0..7 also build WvT hi/lo ----
__global__ __launch_bounds__(256) void k_pass1(const float* __restrict__ q,
                                               const float* __restrict__ Wk,
                                               const float* __restrict__ Wv,
                                               float* __restrict__ agg,
                                               unsigned short* __restrict__ WvTh,
                                               unsigned short* __restrict__ WvTl) {
  const int blk = blockIdx.x;
  const int c = blk & (NCH - 1);
  const int b = blk >> 8;

  __shared__ float SH[64 * QSTR];           // Qs (32xQSTR); reused for Wv transpose
  __shared__ float Wks[PP * DD];
  __shared__ float cks[PP * TSTR], sks[PP * TSTR];

  const int tid = threadIdx.x;
  const float* qb = q + ((size_t)b * TT + (size_t)c * CC) * DD;
  for (int g = tid; g < CC * DD; g += 256) SH[(g >> 6) * QSTR + (g & 63)] = qb[g];
  for (int g = tid; g < PP * DD; g += 256) Wks[g] = Wk[g];
  __syncthreads();

  {  // k-dots + trig: thread = (t, p)
    const int t = tid & 31, p = tid >> 5;
    float dk = 0.f;
    const float4* qr = (const float4*)&SH[t * QSTR];
    const float4* wr = (const float4*)&Wks[p * DD];
#pragma unroll
    for (int j = 0; j < 16; ++j) {
      float4 qv = qr[j], wv = wr[j];
      dk = fmaf(qv.x, wv.x, dk); dk = fmaf(qv.y, wv.y, dk);
      dk = fmaf(qv.z, wv.z, dk); dk = fmaf(qv.w, wv.w, dk);
    }
    float ang = fast_tanh(dk) * KPI4;
    cks[p * TSTR + t] = __cosf(ang);
    sks[p * TSTR + t] = __sinf(ang);
  }
  __syncthreads();

  {  // d-space aggregates: thread = (i, p-pair)
    const int i = tid & 63, pq = tid >> 6;
    const int p0 = pq, p1 = pq + 4;
    float c0 = 0, s0 = 0, c1 = 0, s1 = 0;
#pragma unroll
    for (int t = 0; t < CC; ++t) {
      float qv = SH[t * QSTR + i];
      c0 = fmaf(cks[p0 * TSTR + t], qv, c0);
      s0 = fmaf(sks[p0 * TSTR + t], qv, s0);
      c1 = fmaf(cks[p1 * TSTR + t], qv, c1);
      s1 = fmaf(sks[p1 * TSTR + t], qv, s1);
    }
    float* a0 = agg + (size_t)((b * PP + p0) * NCH + c) * AGG_STRIDE;
    float* a1 = agg + (size_t)((b * PP + p1) * NCH + c) * AGG_STRIDE;
    a0[i] = c0; a0[64 + i] = s0;
    a1[i] = c1; a1[64 + i] = s1;
  }
  if (tid < 16) {  // scalar cos/sin sums
    const int p = tid & 7;
    float s2 = 0.f;
    if (tid < 8) {
      for (int t = 0; t < CC; ++t) s2 += cks[p * TSTR + t];
      agg[(size_t)((b * PP + p) * NCH + c) * AGG_STRIDE + 128] = s2;
    } else {
      for (int t = 0; t < CC; ++t) s2 += sks[p * TSTR + t];
      agg[(size_t)((b * PP + p) * NCH + c) * AGG_STRIDE + 129] = s2;
    }
  }

  // Wv transpose + double-bf16 split: blocks 0..7, one 64-k tile each.
  if (blk < 8) {
    __syncthreads();
    const int k0 = blk * 64;
    for (int idx = tid; idx < 4096; idx += 256) {
      int kk = idx >> 6, o = idx & 63;                    // coalesced over o
      SH[o * QSTR + kk] = Wv[(size_t)(k0 + kk) * DD + o];
    }
    __syncthreads();
    for (int idx = tid; idx < 4096; idx += 256) {
      int o = idx >> 6, kk = idx & 63;                    // coalesced over kk
      float wv = SH[o * QSTR + kk];
      unsigned short hi = f2bf(wv);
      WvTh[(size_t)o * 512 + k0 + kk] = hi;
      WvTl[(size_t)o * 512 + k0 + kk] = f2bf(wv - bf2f(hi));
    }
  }
}

// ---- Pass 2: exclusive scan over chunks, in place ----
__global__ __launch_bounds__(256) void k_pass2(float* __restrict__ agg) {
  const int bp = blockIdx.x;
  const int j = threadIdx.x;
  if (j >= AGG_STRIDE) return;
  size_t base = (size_t)bp * NCH * AGG_STRIDE + j;
  float run = 0.f;
#pragma unroll 8
  for (int ch = 0; ch < NCH; ++ch) {
    size_t idx = base + (size_t)ch * AGG_STRIDE;
    float v = agg[idx];
    agg[idx] = run;
    run += v;
  }
}

// ---- Pass 3: trig + scan -> Z(hi/lo bf16) per p-half -> 3-term MFMA GEMM ----
__global__ __launch_bounds__(256) void k_pass3(
    const float* __restrict__ q, const float* __restrict__ Wq,
    const float* __restrict__ Wk, const float* __restrict__ Wo,
    const float* __restrict__ pref,
    const unsigned short* __restrict__ WvTh,
    const unsigned short* __restrict__ WvTl,
    float* __restrict__ out) {
  const int blk = blockIdx.x;
  const int c = blk & (NCH - 1);
  const int b = blk >> 8;

  __shared__ float Qs[CC * QSTR];                          // 8.5 KB
  __shared__ float Wqs[PP * DD], Wks[PP * DD];             // 4 KB
  __shared__ float cqs[PP * TSTR], sqs[PP * TSTR];         // 2.1 KB
  __shared__ float cks[PP * TSTR], sks[PP * TSTR];         // 2.1 KB
  __shared__ float scs[PP * TSTR];                         // 1.06 KB
  __shared__ __align__(16) short Zh[CC * ZSTR];            // 16.9 KB
  __shared__ __align__(16) short Zl[CC * ZSTR];            // 16.9 KB

  const int tid = threadIdx.x;
  const float* qb = q + ((size_t)b * TT + (size_t)c * CC) * DD;
  for (int g = tid; g < CC * DD; g += 256) Qs[(g >> 6) * QSTR + (g & 63)] = qb[g];
  for (int g = tid; g < PP * DD; g += 256) { Wqs[g] = Wq[g]; Wks[g] = Wk[g]; }
  __syncthreads();

  // Phase A: q/k dots + trig. thread = (t, p).
  {
    const int t = tid & 31, p = tid >> 5;
    float dq = 0.f, dk = 0.f;
    const float4* qr  = (const float4*)&Qs[t * QSTR];
    const float4* wqr = (const float4*)&Wqs[p * DD];
    const float4* wkr = (const float4*)&Wks[p * DD];
#pragma unroll
    for (int j = 0; j < 16; ++j) {
      float4 qv = qr[j], w0 = wqr[j], w1 = wkr[j];
      dq = fmaf(qv.x, w0.x, dq); dq = fmaf(qv.y, w0.y, dq);
      dq = fmaf(qv.z, w0.z, dq); dq = fmaf(qv.w, w0.w, dq);
      dk = fmaf(qv.x, w1.x, dk); dk = fmaf(qv.y, w1.y, dk);
      dk = fmaf(qv.z, w1.z, dk); dk = fmaf(qv.w, w1.w, dk);
    }
    float ang = fast_tanh(dq) * KPI4;
    cqs[p * TSTR + t] = __cosf(ang); sqs[p * TSTR + t] = __sinf(ang);
    ang = fast_tanh(dk) * KPI4;
    cks[p * TSTR + t] = __cosf(ang); sks[p * TSTR + t] = __sinf(ang);
  }
  __syncthreads();

  // Phase A2: per-p serial scan of cos/sin-K -> sc[t] = Wo_p / den[t].
  if (tid < PP) {
    const int p = tid;
    const float* pr = pref + (size_t)((b * PP + p) * NCH + c) * AGG_STRIDE;
    float rc = pr[128], rs = pr[129];
    const float wo = Wo[p];
    for (int t = 0; t < CC; ++t) {
      rc += cks[p * TSTR + t];
      rs += sks[p * TSTR + t];
      float den = fmaf(cqs[p * TSTR + t], rc, fmaf(sqs[p * TSTR + t], rs, EPSV));
      scs[p * TSTR + t] = wo * __builtin_amdgcn_rcpf(den);
    }
  }
  __syncthreads();

  const int w = tid >> 6, l = tid & 63;
  const int tr = (w & 1) << 4;       // t-tile row
  const int oc = (w >> 1) << 5;      // o-tile col (two 16-wide tiles)
  const int lm = l & 15, lg = l >> 4;
  f32x4 acc0 = {0, 0, 0, 0}, acc1 = {0, 0, 0, 0};

#pragma unroll
  for (int h = 0; h < 2; ++h) {
    {  // Phase B(h): thread = (i, ph); wave == ph; p = h*4+ph.
      const int i = tid & 63, ph = tid >> 6;
      const int p = h * 4 + ph;
      const float* pr = pref + (size_t)((b * PP + p) * NCH + c) * AGG_STRIDE;
      float Ac = pr[i], As = pr[64 + i];
#pragma unroll 8
      for (int t = 0; t < CC; ++t) {
        float qv = Qs[t * QSTR + i];
        Ac = fmaf(cks[p * TSTR + t], qv, Ac);
        As = fmaf(sks[p * TSTR + t], qv, As);
        float z = scs[p * TSTR + t] * fmaf(cqs[p * TSTR + t], Ac, sqs[p * TSTR + t] * As);
        unsigned short hi = f2bf(z);
        Zh[t * ZSTR + ph * 64 + i] = (short)hi;
        Zl[t * ZSTR + ph * 64 + i] = (short)f2bf(z - bf2f(hi));
      }
    }
    __syncthreads();
    {  // Phase C(h): 3-term double-bf16 MFMA accumulate.
      const short* zha = &Zh[(tr + lm) * ZSTR + lg * 8];
      const short* zla = &Zl[(tr + lm) * ZSTR + lg * 8];
      const unsigned short* bh0 = &WvTh[(size_t)(oc + lm) * 512 + h * 256 + lg * 8];
      const unsigned short* bh1 = bh0 + (size_t)16 * 512;
      const unsigned short* bl0 = &WvTl[(size_t)(oc + lm) * 512 + h * 256 + lg * 8];
      const unsigned short* bl1 = bl0 + (size_t)16 * 512;
#pragma unroll
      for (int kk = 0; kk < 8; ++kk) {
        short8 ah  = *(const short8*)(zha + kk * 32);
        short8 al  = *(const short8*)(zla + kk * 32);
        short8 b0h = *(const short8*)(bh0 + kk * 32);
        short8 b1h = *(const short8*)(bh1 + kk * 32);
        short8 b0l = *(const short8*)(bl0 + kk * 32);
        short8 b1l = *(const short8*)(bl1 + kk * 32);
        acc0 = __builtin_amdgcn_mfma_f32_16x16x32_bf16(ah, b0h, acc0, 0, 0, 0);
        acc1 = __builtin_amdgcn_mfma_f32_16x16x32_bf16(ah, b1h, acc1, 0, 0, 0);
        acc0 = __builtin_amdgcn_mfma_f32_16x16x32_bf16(al, b0h, acc0, 0, 0, 0);
        acc1 = __builtin_amdgcn_mfma_f32_16x16x32_bf16(al, b1h, acc1, 0, 0, 0);
        acc0 = __builtin_amdgcn_mfma_f32_16x16x32_bf16(ah, b0l, acc0, 0, 0, 0);
        acc1 = __builtin_amdgcn_mfma_f32_16x16x32_bf16(ah, b1l, acc1, 0, 0, 0);
      }
    }
    __syncthreads();  // protect Zh/Zl before next half's phase B
  }

  // Epilogue: C/D layout col=lane&15, row=(lane>>4)*4+reg  [m89]
  {
    float* ob = out + ((size_t)b * TT + (size_t)c * CC + tr + lg * 4) * DD;
#pragma unroll
    for (int r = 0; r < 4; ++r) {
      ob[r * DD + oc + lm] = acc0[r];
      ob[r * DD + oc + 16 + lm] = acc1[r];
    }
  }
}

extern "C" void kernel_launch(void* const* d_in, const int* in_sizes, int n_in,
                              void* d_out, int out_size, void* d_ws, size_t ws_size,
                              hipStream_t stream) {
  const float* q  = (const float*)d_in[0];
  const float* Wq = (const float*)d_in[1];
  const float* Wk = (const float*)d_in[2];
  const float* Wv = (const float*)d_in[3];
  const float* Wo = (const float*)d_in[4];
  float* out = (float*)d_out;
  float* agg = (float*)d_ws;  // BB*PP*NCH*130 floats = 4,259,840 B
  unsigned short* WvTh = (unsigned short*)(agg + (size_t)BB * PP * NCH * AGG_STRIDE);
  unsigned short* WvTl = WvTh + (size_t)512 * 64;   // +64 KB each

  k_pass1<<<BB * NCH, 256, 0, stream>>>(q, Wk, Wv, agg, WvTh, WvTl);
  k_pass2<<<BB * PP, 256, 0, stream>>>(agg);
  k_pass3<<<BB * NCH, 256, 0, stream>>>(q, Wq, Wk, Wo, agg, WvTh, WvTl, out);
}

// Round 4
// 48.751 us; speedup vs baseline: 2.0392x; 1.4161x over previous
//
#include <hip/hip_runtime.h>
#include <hip/hip_bf16.h>
#include <math.h>

#define BB  4
#define TT  8192
#define DD  64
#define PP  8
#define CC  32            // chunk length along t
#define NCH (TT/CC)       // 256 chunks
#define QSTR 68           // padded Q row stride (floats)
#define TSTR 33           // padded per-p trig stride

#define EPSV 1e-3f
#define KPI4 0.78539816339744830962f

typedef __attribute__((ext_vector_type(8))) short short8;   // 8 bf16
typedef __attribute__((ext_vector_type(4))) float f32x4;

__device__ __forceinline__ float bf2f(unsigned short h) {
  return __uint_as_float(((unsigned)h) << 16);
}
__device__ __forceinline__ unsigned short f2bf(float f) {   // RNE
  unsigned u = __float_as_uint(f);
  u += 0x7fffu + ((u >> 16) & 1u);
  return (unsigned short)(u >> 16);
}
__device__ __forceinline__ float fast_tanh(float x) {
  float e = __expf(2.f * x);
  return 1.f - 2.f * __builtin_amdgcn_rcpf(e + 1.f);
}
// Z swizzle: row stride 512B, XOR byte-bits 4..6 by row&7 (quad-uniform b128 reads)
__device__ __forceinline__ int zswz(int row, int kb) {
  return (row << 9) + (kb ^ ((row & 7) << 4));
}

// ---- Pass 1: per-(b,chunk) aggregates; blocks 0..7 also build WvT hi/lo ----
__global__ __launch_bounds__(256) void k_pass1(const float* __restrict__ q,
                                               const float* __restrict__ Wk,
                                               const float* __restrict__ Wv,
                                               float* __restrict__ aggC,
                                               float* __restrict__ aggS,
                                               unsigned short* __restrict__ WvTh,
                                               unsigned short* __restrict__ WvTl) {
  const int blk = blockIdx.x;
  const int c = blk & (NCH - 1);
  const int b = blk >> 8;

  __shared__ float SH[64 * QSTR];           // Qs (32 rows); reused for Wv transpose
  __shared__ float Wks[PP * DD];
  __shared__ float cks[PP * TSTR], sks[PP * TSTR];

  const int tid = threadIdx.x;
  const float* qb = q + ((size_t)b * TT + (size_t)c * CC) * DD;
  for (int g = tid; g < CC * DD; g += 256) SH[(g >> 6) * QSTR + (g & 63)] = qb[g];
  for (int g = tid; g < PP * DD; g += 256) Wks[g] = Wk[g];
  __syncthreads();

  {  // k-dots + trig + shfl-reduce sums: thread = (t, p)
    const int t = tid & 31, p = tid >> 5;
    float dk = 0.f;
    const float4* qr = (const float4*)&SH[t * QSTR];
    const float4* wr = (const float4*)&Wks[p * DD];
#pragma unroll
    for (int j = 0; j < 16; ++j) {
      float4 qv = qr[j], wv = wr[j];
      dk = fmaf(qv.x, wv.x, dk); dk = fmaf(qv.y, wv.y, dk);
      dk = fmaf(qv.z, wv.z, dk); dk = fmaf(qv.w, wv.w, dk);
    }
    float ang = fast_tanh(dk) * KPI4;
    float ck = __cosf(ang), sk = __sinf(ang);
    cks[p * TSTR + t] = ck;
    sks[p * TSTR + t] = sk;
    float rc = ck, rs = sk;
#pragma unroll
    for (int d = 16; d >= 1; d >>= 1) {
      rc += __shfl_xor(rc, d, 32);
      rs += __shfl_xor(rs, d, 32);
    }
    if (t == 0) {
      float* s = aggS + ((size_t)(b * PP + p) * NCH + c) * 2;
      s[0] = rc; s[1] = rs;
    }
  }
  __syncthreads();

  {  // d-space aggregates: thread = (i, p-pair)
    const int i = tid & 63, pq = tid >> 6;
    const int p0 = pq, p1 = pq + 4;
    float c0 = 0, s0 = 0, c1 = 0, s1 = 0;
#pragma unroll
    for (int t = 0; t < CC; ++t) {
      float qv = SH[t * QSTR + i];
      c0 = fmaf(cks[p0 * TSTR + t], qv, c0);
      s0 = fmaf(sks[p0 * TSTR + t], qv, s0);
      c1 = fmaf(cks[p1 * TSTR + t], qv, c1);
      s1 = fmaf(sks[p1 * TSTR + t], qv, s1);
    }
    float* a0 = aggC + ((size_t)(b * PP + p0) * NCH + c) * 128;
    float* a1 = aggC + ((size_t)(b * PP + p1) * NCH + c) * 128;
    a0[i] = c0; a0[64 + i] = s0;
    a1[i] = c1; a1[64 + i] = s1;
  }

  // Wv transpose + double-bf16 split: blocks 0..7, one 64-k tile each.
  if (blk < 8) {
    __syncthreads();
    const int k0 = blk * 64;
    for (int idx = tid; idx < 4096; idx += 256) {
      int kk = idx >> 6, o = idx & 63;                    // coalesced over o
      SH[o * QSTR + kk] = Wv[(size_t)(k0 + kk) * DD + o];
    }
    __syncthreads();
    for (int idx = tid; idx < 4096; idx += 256) {
      int o = idx >> 6, kk = idx & 63;                    // coalesced over kk
      float wv = SH[o * QSTR + kk];
      unsigned short hi = f2bf(wv);
      WvTh[(size_t)o * 512 + k0 + kk] = hi;
      WvTl[(size_t)o * 512 + k0 + kk] = f2bf(wv - bf2f(hi));
    }
  }
}

// ---- Pass 2: hierarchical exclusive scan over 256 chunks, 4-way segmented ----
// 130 streams per bp (128 d-space + 2 scalar), 4 segments of 64 chunks.
__global__ __launch_bounds__(576) void k_pass2(float* __restrict__ aggC,
                                               float* __restrict__ aggS) {
  const int bp = blockIdx.x;
  const int tid = threadIdx.x;
  __shared__ float totals[4][132];

  const bool act = tid < 520;
  int seg = 0, m = 0;
  float* base = aggC;
  int stride = 128;
  float vals[64];
  if (act) {
    seg = tid / 130;
    m = tid - seg * 130;
    if (m < 128) { base = aggC + (size_t)bp * NCH * 128 + m; stride = 128; }
    else         { base = aggS + (size_t)bp * NCH * 2 + (m - 128); stride = 2; }
    float run = 0.f;
#pragma unroll
    for (int u = 0; u < 64; ++u) vals[u] = base[(size_t)(seg * 64 + u) * stride];
#pragma unroll
    for (int u = 0; u < 64; ++u) run += vals[u];
    totals[seg][m] = run;
  }
  __syncthreads();
  if (act) {
    float r2 = 0.f;
    for (int s = 0; s < seg; ++s) r2 += totals[s][m];
#pragma unroll
    for (int u = 0; u < 64; ++u) {
      float v = vals[u];
      base[(size_t)(seg * 64 + u) * stride] = r2;
      r2 += v;
    }
  }
}

// ---- Pass 3: trig+scan -> Z(hi/lo bf16, swizzled) -> 3-term MFMA GEMM ----
__global__ __launch_bounds__(256, 3) void k_pass3(
    const float* __restrict__ q, const float* __restrict__ Wq,
    const float* __restrict__ Wk, const float* __restrict__ Wo,
    const float* __restrict__ aggC, const float* __restrict__ aggS,
    const unsigned short* __restrict__ WvTh,
    const unsigned short* __restrict__ WvTl,
    float* __restrict__ out) {
  const int blk = blockIdx.x;
  const int c = blk & (NCH - 1);
  const int b = blk >> 8;

  __shared__ float Qs[CC * QSTR];                          // 8.7 KB
  __shared__ float Wqs[PP * DD], Wks[PP * DD];             // 4 KB
  __shared__ float cqs[PP * TSTR], sqs[PP * TSTR];         // 2.1 KB
  __shared__ float cks[PP * TSTR], sks[PP * TSTR];         // 2.1 KB
  __shared__ float scs[PP * TSTR];                         // 1.06 KB
  __shared__ __align__(16) short Zh[CC * 256];             // 16 KB (swizzled)
  __shared__ __align__(16) short Zl[CC * 256];             // 16 KB

  const int tid = threadIdx.x;
  const int w = tid >> 6, l = tid & 63;
  const int lm = l & 15, lg = l >> 4;
  const int oc = w << 4;                                   // wave's 16 o-cols

  // Prefetch h=0 B-fragments (WvT) into registers — independent of all LDS.
  short8 bhf[8], blf[8];
  {
    const unsigned short* ph_ = WvTh + (size_t)(oc + lm) * 512 + lg * 8;
    const unsigned short* pl_ = WvTl + (size_t)(oc + lm) * 512 + lg * 8;
#pragma unroll
    for (int kk = 0; kk < 8; ++kk) {
      bhf[kk] = *(const short8*)(ph_ + kk * 32);
      blf[kk] = *(const short8*)(pl_ + kk * 32);
    }
  }

  const float* qb = q + ((size_t)b * TT + (size_t)c * CC) * DD;
  for (int g = tid; g < CC * DD; g += 256) Qs[(g >> 6) * QSTR + (g & 63)] = qb[g];
  for (int g = tid; g < PP * DD; g += 256) { Wqs[g] = Wq[g]; Wks[g] = Wk[g]; }
  __syncthreads();

  // Phase A: dots + trig + in-wave prefix scan of cos/sin-K -> scs.
  {
    const int t = tid & 31, p = tid >> 5;
    float dq = 0.f, dk = 0.f;
    const float4* qr  = (const float4*)&Qs[t * QSTR];
    const float4* wqr = (const float4*)&Wqs[p * DD];
    const float4* wkr = (const float4*)&Wks[p * DD];
#pragma unroll
    for (int j = 0; j < 16; ++j) {
      float4 qv = qr[j], w0 = wqr[j], w1 = wkr[j];
      dq = fmaf(qv.x, w0.x, dq); dq = fmaf(qv.y, w0.y, dq);
      dq = fmaf(qv.z, w0.z, dq); dq = fmaf(qv.w, w0.w, dq);
      dk = fmaf(qv.x, w1.x, dk); dk = fmaf(qv.y, w1.y, dk);
      dk = fmaf(qv.z, w1.z, dk); dk = fmaf(qv.w, w1.w, dk);
    }
    float ang = fast_tanh(dq) * KPI4;
    float cq = __cosf(ang), sq = __sinf(ang);
    ang = fast_tanh(dk) * KPI4;
    float ck = __cosf(ang), sk = __sinf(ang);
    cqs[p * TSTR + t] = cq; sqs[p * TSTR + t] = sq;
    cks[p * TSTR + t] = ck; sks[p * TSTR + t] = sk;
    // inclusive scan over t within each 32-lane segment
    float rc = ck, rs = sk;
#pragma unroll
    for (int d = 1; d < 32; d <<= 1) {
      float tc = __shfl_up(rc, (unsigned)d, 32);
      float ts = __shfl_up(rs, (unsigned)d, 32);
      if (t >= d) { rc += tc; rs += ts; }
    }
    const float* sgl = aggS + ((size_t)(b * PP + p) * NCH + c) * 2;
    rc += sgl[0]; rs += sgl[1];
    float den = fmaf(cq, rc, fmaf(sq, rs, EPSV));
    scs[p * TSTR + t] = Wo[p] * __builtin_amdgcn_rcpf(den);
  }
  __syncthreads();

  f32x4 acc0 = {0, 0, 0, 0}, acc1 = {0, 0, 0, 0};

#pragma unroll
  for (int h = 0; h < 2; ++h) {
    {  // Phase B(h): thread = (i=l, ph=w); p = h*4+w; k_half = w*64+l.
      const int p = h * 4 + w;
      const float* prC = aggC + ((size_t)(b * PP + p) * NCH + c) * 128;
      float Ac = prC[l], As = prC[64 + l];
      const int kb = (w * 64 + l) * 2;     // byte offset of this k in a Z row
#pragma unroll 8
      for (int t = 0; t < CC; ++t) {
        float qv = Qs[t * QSTR + l];
        Ac = fmaf(cks[p * TSTR + t], qv, Ac);
        As = fmaf(sks[p * TSTR + t], qv, As);
        float z = scs[p * TSTR + t] * fmaf(cqs[p * TSTR + t], Ac, sqs[p * TSTR + t] * As);
        unsigned u = __float_as_uint(z);
        unsigned r = u + 0x7fffu + ((u >> 16) & 1u);
        int zb = zswz(t, kb);
        ((unsigned short*)Zh)[zb >> 1] = (unsigned short)(r >> 16);
        float lo = z - __uint_as_float(r & 0xffff0000u);
        ((unsigned short*)Zl)[zb >> 1] = (unsigned short)(__float_as_uint(lo) >> 16);
      }
    }
    __syncthreads();
    // Phase C(h): pure ds_read + MFMA (B-frags already in registers).
#pragma unroll
    for (int kk = 0; kk < 8; ++kk) {
      const int rb0 = zswz(lm, kk * 64 + lg * 16);
      const int rb1 = zswz(16 + lm, kk * 64 + lg * 16);
      short8 ah0 = *(const short8*)((const char*)Zh + rb0);
      short8 al0 = *(const short8*)((const char*)Zl + rb0);
      short8 ah1 = *(const short8*)((const char*)Zh + rb1);
      short8 al1 = *(const short8*)((const char*)Zl + rb1);
      acc0 = __builtin_amdgcn_mfma_f32_16x16x32_bf16(ah0, bhf[kk], acc0, 0, 0, 0);
      acc1 = __builtin_amdgcn_mfma_f32_16x16x32_bf16(ah1, bhf[kk], acc1, 0, 0, 0);
      acc0 = __builtin_amdgcn_mfma_f32_16x16x32_bf16(al0, bhf[kk], acc0, 0, 0, 0);
      acc1 = __builtin_amdgcn_mfma_f32_16x16x32_bf16(al1, bhf[kk], acc1, 0, 0, 0);
      acc0 = __builtin_amdgcn_mfma_f32_16x16x32_bf16(ah0, blf[kk], acc0, 0, 0, 0);
      acc1 = __builtin_amdgcn_mfma_f32_16x16x32_bf16(ah1, blf[kk], acc1, 0, 0, 0);
    }
    if (h == 0) {  // prefetch h=1 B-fragments; latency hides under B(1)
      const unsigned short* ph_ = WvTh + (size_t)(oc + lm) * 512 + 256 + lg * 8;
      const unsigned short* pl_ = WvTl + (size_t)(oc + lm) * 512 + 256 + lg * 8;
#pragma unroll
      for (int kk = 0; kk < 8; ++kk) {
        bhf[kk] = *(const short8*)(ph_ + kk * 32);
        blf[kk] = *(const short8*)(pl_ + kk * 32);
      }
    }
    __syncthreads();
  }

  // Epilogue: C/D layout col=lane&15 (o), row=(lane>>4)*4+reg (t)  [m89]
  {
    float* ob = out + ((size_t)b * TT + (size_t)c * CC + lg * 4) * DD + oc + lm;
#pragma unroll
    for (int r = 0; r < 4; ++r) {
      ob[r * DD] = acc0[r];
      ob[(16 + r) * DD] = acc1[r];
    }
  }
}

extern "C" void kernel_launch(void* const* d_in, const int* in_sizes, int n_in,
                              void* d_out, int out_size, void* d_ws, size_t ws_size,
                              hipStream_t stream) {
  const float* q  = (const float*)d_in[0];
  const float* Wq = (const float*)d_in[1];
  const float* Wk = (const float*)d_in[2];
  const float* Wv = (const float*)d_in[3];
  const float* Wo = (const float*)d_in[4];
  float* out = (float*)d_out;

  float* aggC = (float*)d_ws;                               // 4 MiB
  float* aggS = aggC + (size_t)BB * PP * NCH * 128;         // 64 KiB
  unsigned short* WvTh = (unsigned short*)(aggS + (size_t)BB * PP * NCH * 2);
  unsigned short* WvTl = WvTh + (size_t)512 * 64;           // 64 KiB each

  k_pass1<<<BB * NCH, 256, 0, stream>>>(q, Wk, Wv, aggC, aggS, WvTh, WvTl);
  k_pass2<<<BB * PP, 576, 0, stream>>>(aggC, aggS);
  k_pass3<<<BB * NCH, 256, 0, stream>>>(q, Wq, Wk, Wo, aggC, aggS, WvTh, WvTl, out);
}